// Round 13
// baseline (329.189 us; speedup 1.0000x reference)
//
#include <hip/hip_runtime.h>

// Problem constants
#define NN 50000
#define EE 800000
#define FF 256    // IN = HID = PROJ = 256
#define CAP 64    // edge-slot capacity per dst row (max indeg ~35 for this input)
#define GEMM_BLKS 784
#define XCVT_BLKS 6250  // 50000*256 / (256 thr * 8 elem)
#define FILL_BLKS 3125  // EE/256

typedef float    f32x4 __attribute__((ext_vector_type(4)));
typedef _Float16 f16x8 __attribute__((ext_vector_type(8)));
typedef _Float16 f16x4 __attribute__((ext_vector_type(4)));

// ---------------------------------------------------------------------------
// W pack (swizzled LDS-image) + fused x->fp16 convert + count+fill tails.
// All three block types are LDS-free -> they truly mix on CUs (no round-10
// occupancy cap): streaming cvt hides under fill's atomic latency.
// ---------------------------------------------------------------------------
__global__ void packw_kernel(const float* __restrict__ W1, const float* __restrict__ W2,
                             _Float16* __restrict__ wp,
                             const float* __restrict__ x, _Float16* __restrict__ xh,
                             const int* __restrict__ ei, int* __restrict__ cnt,
                             int* __restrict__ ecw) {
    const int bid = blockIdx.x;
    if (bid >= 64 + XCVT_BLKS) {                // count+fill tail
        int e = (bid - 64 - XCVT_BLKS) * 256 + threadIdx.x;  // FILL_BLKS*256==EE
        int s = ei[e];
        int d = ei[EE + e];
        int slot = atomicAdd(&cnt[d], 1);
        if (slot < CAP) ecw[(size_t)d * CAP + slot] = s;
        return;
    }
    if (bid >= 64) {                            // x -> fp16 convert tail
        size_t i = ((size_t)(bid - 64) * 256 + threadIdx.x) * 8;
        f32x4 v0 = *(const f32x4*)(x + i);
        f32x4 v1 = *(const f32x4*)(x + i + 4);
        f16x8 o;
        o[0] = (_Float16)v0.x; o[1] = (_Float16)v0.y;
        o[2] = (_Float16)v0.z; o[3] = (_Float16)v0.w;
        o[4] = (_Float16)v1.x; o[5] = (_Float16)v1.y;
        o[6] = (_Float16)v1.z; o[7] = (_Float16)v1.w;
        *(f16x8*)(xh + i) = o;
        return;
    }
    int idx = bid * 256 + threadIdx.x;          // 0..16383
    int p   = idx & 511;
    int kt  = (idx >> 9) & 7;
    int nb  = (idx >> 12) & 1;
    int L   = (idx >> 13) & 1;
    const float* W = L ? W2 : W1;
    int rs = p >> 2, cs = p & 3;
    int r  = rs ^ ((rs >> 2) & 1);
    int c  = cs ^ (r & 3);
    int n  = nb * 128 + r;
    int k0 = kt * 32 + c * 8;
    f16x8 hi, lo;
#pragma unroll
    for (int j = 0; j < 8; ++j) {
        float v = W[(size_t)(k0 + j) * 256 + n];
        _Float16 h = (_Float16)v;
        hi[j] = h;
        lo[j] = (_Float16)(v - (float)h);
    }
    size_t ch = ((size_t)((L * 2 + 0) * 2 + nb) * 8 + kt) * 4096;
    size_t cl = ((size_t)((L * 2 + 1) * 2 + nb) * 8 + kt) * 4096;
    *(f16x8*)(wp + ch + (size_t)p * 8) = hi;
    *(f16x8*)(wp + cl + (size_t)p * 8) = lo;
}

// ---------------------------------------------------------------------------
// GEMM, fp16-A-only, counted-vmcnt pipeline (T3/T4).
// Per k-step group = exactly 3 gll16 (Bh, Bl, A), issued 2 steps ahead.
// Loop: wait vmcnt(3) [group kt done, kt+1 STAYS IN FLIGHT across barrier]
//  -> s_barrier -> compute(kt) -> lgkmcnt(0)+s_barrier [buf reusable]
//  -> stage(kt+2 -> freed buf). No vmcnt(0) drain in the main loop.
// Epilogue scales row m by dinv[m]=rsqrt(cnt[m]+1) (h' trick, round 12).
// ---------------------------------------------------------------------------

__device__ __forceinline__ void gll16(const void* g, void* l) {
    __builtin_amdgcn_global_load_lds(
        (const __attribute__((address_space(1))) void*)g,
        (__attribute__((address_space(3))) void*)l, 16, 0, 0);
}

__global__ __launch_bounds__(512) void gemm_kernel(
    const _Float16* __restrict__ X, const _Float16* __restrict__ Bhi,
    const _Float16* __restrict__ Blo, _Float16* __restrict__ H,
    const int* __restrict__ cnt) {
    __shared__ __align__(16) _Float16 Bh[2][4096];   // 16 KB
    __shared__ __align__(16) _Float16 Bl[2][4096];   // 16 KB
    __shared__ __align__(16) _Float16 As[2][4096];   // 16 KB

    // de-swizzle linear gemm id -> (pair p, member nb) with same-XCD pairing
    const int gid = blockIdx.x;
    const int p_  = (gid >> 4) * 8 + (gid & 7);
    const int nb  = (gid >> 3) & 1;
    if (p_ >= 391) return;                       // whole block, pre-barrier

    const int tid = threadIdx.x;
    const int ln  = tid & 63;
    const int w   = tid >> 6;        // 0..7
    const int wm  = w & 1;           // 2 x 64 rows
    const int wn  = w >> 1;          // 4 x 32 cols
    const int q   = ln >> 4;         // k-group
    const int l16 = ln & 15;
    const int m0  = p_ * 128;
    const size_t bchunk = (size_t)nb * 8 * 4096;

    // A staging geometry: granule g holds row r_, col-granule c_ of the
    // swizzled fp16 image, stored linearly at g*16B.
    const int g   = w * 64 + ln;                  // granule 0..511
    const int rs_ = g >> 2, cs_ = g & 3;
    const int r_  = rs_ ^ ((rs_ >> 2) & 1);
    const int c_  = cs_ ^ (r_ & 3);
    int gm_ = m0 + r_; if (gm_ > NN - 1) gm_ = NN - 1;

    f32x4 acc[4][2] = {};            // [mt][nt]

    auto stage = [&](int kt, int buf) {           // exactly 3 gll16 / wave
        gll16(Bhi + bchunk + (size_t)kt * 4096 + (size_t)g * 8,
              &Bh[buf][w * 512]);
        gll16(Blo + bchunk + (size_t)kt * 4096 + (size_t)g * 8,
              &Bl[buf][w * 512]);
        gll16(X + (size_t)gm_ * FF + kt * 32 + c_ * 8,
              (_Float16*)&As[buf][0] + (size_t)(w * 64) * 8);
    };

    auto compute = [&](int buf) {
        f16x8 af[4], bhf[2], blf[2];
#pragma unroll
        for (int mt = 0; mt < 4; ++mt) {
            int r  = wm * 64 + mt * 16 + l16;
            int rr = r ^ ((r >> 2) & 1);
            af[mt] = *(const f16x8*)(&As[buf][(rr * 4 + (q ^ (r & 3))) * 8]);
        }
#pragma unroll
        for (int nt = 0; nt < 2; ++nt) {
            int r  = wn * 32 + nt * 16 + l16;
            int rr = r ^ ((r >> 2) & 1);
            int off = (rr * 4 + (q ^ (r & 3))) * 8;
            bhf[nt] = *(const f16x8*)(&Bh[buf][off]);
            blf[nt] = *(const f16x8*)(&Bl[buf][off]);
        }
#pragma unroll
        for (int mt = 0; mt < 4; ++mt)
#pragma unroll
            for (int nt = 0; nt < 2; ++nt) {
                acc[mt][nt] = __builtin_amdgcn_mfma_f32_16x16x32_f16(af[mt], bhf[nt], acc[mt][nt], 0, 0, 0);
                acc[mt][nt] = __builtin_amdgcn_mfma_f32_16x16x32_f16(af[mt], blf[nt], acc[mt][nt], 0, 0, 0);
            }
    };

    stage(0, 0);                     // in flight: 3
    stage(1, 1);                     // in flight: 6
    int cur = 0;
#pragma unroll
    for (int kt = 0; kt < 8; ++kt) {
        if (kt < 7) { asm volatile("s_waitcnt vmcnt(3)" ::: "memory"); }
        else        { asm volatile("s_waitcnt vmcnt(0)" ::: "memory"); }
        __builtin_amdgcn_sched_barrier(0);
        asm volatile("s_barrier" ::: "memory");   // group kt valid block-wide
        __builtin_amdgcn_sched_barrier(0);
        compute(cur);
        __builtin_amdgcn_sched_barrier(0);
        asm volatile("s_waitcnt lgkmcnt(0)" ::: "memory");  // ds_reads done
        asm volatile("s_barrier" ::: "memory");   // all readers done: buf free
        __builtin_amdgcn_sched_barrier(0);
        if (kt + 2 < 8) stage(kt + 2, cur);       // refill freed buffer
        cur ^= 1;
    }

    // epilogue: row-major H, each row m scaled by dinv[m] = rsqrt(cnt[m]+1)
#pragma unroll
    for (int mt = 0; mt < 4; ++mt)
#pragma unroll
        for (int r4 = 0; r4 < 4; ++r4) {
            int m = m0 + wm * 64 + mt * 16 + q * 4 + r4;
            if (m < NN) {
                float sc = rsqrtf((float)(cnt[m] + 1));
#pragma unroll
                for (int nt = 0; nt < 2; ++nt) {
                    int n = nb * 128 + wn * 32 + nt * 16 + l16;
                    H[(size_t)m * FF + n] = (_Float16)(acc[mt][nt][r4] * sc);
                }
            }
        }
}

// ---------------------------------------------------------------------------
// Aggregation + bias + PReLU (unchanged, round-12 passing form).
// H holds h' = dinv*h; records are src-only; di = rsqrt(cnt[i]+1).
// ---------------------------------------------------------------------------
template<typename OT>
__global__ __launch_bounds__(256) void agg_kernel(
    const _Float16* __restrict__ H, const int* __restrict__ cnt,
    const int* __restrict__ ecw, const float* __restrict__ bias,
    const float* __restrict__ a_ptr, OT* __restrict__ out) {
    const int row  = blockIdx.x * 4 + (threadIdx.x >> 6);
    const int lane = threadIdx.x & 63;
    if (row >= NN) return;

    const float av  = a_ptr[0];
    const int   deg = cnt[row];
    const float di  = rsqrtf((float)(deg + 1));
    const int   end = (deg < CAP) ? deg : CAP;
    const int*  er  = ecw + (size_t)row * CAP;

    f16x4 hv = *(const f16x4*)(H + (size_t)row * FF + lane * 4);
    float ax = (float)hv.x;
    float ay = (float)hv.y;
    float az = (float)hv.z;
    float aw = (float)hv.w;

    int e = 0;
    for (; e + 7 < end; e += 8) {               // 8 gathers in flight
        int4 q0 = *(const int4*)(er + e);
        int4 q1 = *(const int4*)(er + e + 4);
        f16x4 h0 = *(const f16x4*)(H + (size_t)q0.x * FF + lane * 4);
        f16x4 h1 = *(const f16x4*)(H + (size_t)q0.y * FF + lane * 4);
        f16x4 h2 = *(const f16x4*)(H + (size_t)q0.z * FF + lane * 4);
        f16x4 h3 = *(const f16x4*)(H + (size_t)q0.w * FF + lane * 4);
        f16x4 h4 = *(const f16x4*)(H + (size_t)q1.x * FF + lane * 4);
        f16x4 h5 = *(const f16x4*)(H + (size_t)q1.y * FF + lane * 4);
        f16x4 h6 = *(const f16x4*)(H + (size_t)q1.z * FF + lane * 4);
        f16x4 h7 = *(const f16x4*)(H + (size_t)q1.w * FF + lane * 4);
        ax += ((float)h0.x + (float)h1.x) + ((float)h2.x + (float)h3.x)
            + ((float)h4.x + (float)h5.x) + ((float)h6.x + (float)h7.x);
        ay += ((float)h0.y + (float)h1.y) + ((float)h2.y + (float)h3.y)
            + ((float)h4.y + (float)h5.y) + ((float)h6.y + (float)h7.y);
        az += ((float)h0.z + (float)h1.z) + ((float)h2.z + (float)h3.z)
            + ((float)h4.z + (float)h5.z) + ((float)h6.z + (float)h7.z);
        aw += ((float)h0.w + (float)h1.w) + ((float)h2.w + (float)h3.w)
            + ((float)h4.w + (float)h5.w) + ((float)h6.w + (float)h7.w);
    }
    for (; e + 3 < end; e += 4) {               // 4-deep remainder
        int4 q0 = *(const int4*)(er + e);
        f16x4 h0 = *(const f16x4*)(H + (size_t)q0.x * FF + lane * 4);
        f16x4 h1 = *(const f16x4*)(H + (size_t)q0.y * FF + lane * 4);
        f16x4 h2 = *(const f16x4*)(H + (size_t)q0.z * FF + lane * 4);
        f16x4 h3 = *(const f16x4*)(H + (size_t)q0.w * FF + lane * 4);
        ax += ((float)h0.x + (float)h1.x) + ((float)h2.x + (float)h3.x);
        ay += ((float)h0.y + (float)h1.y) + ((float)h2.y + (float)h3.y);
        az += ((float)h0.z + (float)h1.z) + ((float)h2.z + (float)h3.z);
        aw += ((float)h0.w + (float)h1.w) + ((float)h2.w + (float)h3.w);
    }
    for (; e < end; ++e) {
        int s = er[e];
        f16x4 h0 = *(const f16x4*)(H + (size_t)s * FF + lane * 4);
        ax += (float)h0.x;
        ay += (float)h0.y;
        az += (float)h0.z;
        aw += (float)h0.w;
    }

    f32x4 bv = *(const f32x4*)(bias + lane * 4);
    float r0 = di * ax + bv.x; r0 = (r0 >= 0.f) ? r0 : av * r0;
    float r1 = di * ay + bv.y; r1 = (r1 >= 0.f) ? r1 : av * r1;
    float r2 = di * az + bv.z; r2 = (r2 >= 0.f) ? r2 : av * r2;
    float r3 = di * aw + bv.w; r3 = (r3 >= 0.f) ? r3 : av * r3;
    if constexpr (sizeof(OT) == 4) {
        f32x4 res = {r0, r1, r2, r3};
        *(f32x4*)((float*)out + (size_t)row * FF + lane * 4) = res;
    } else {
        f16x4 res;
        res.x = (_Float16)r0; res.y = (_Float16)r1;
        res.z = (_Float16)r2; res.w = (_Float16)r3;
        *(f16x4*)((_Float16*)out + (size_t)row * FF + lane * 4) = res;
    }
}

// ---------------------------------------------------------------------------
// Launch: 5 kernels + 1 memset. xh aliases h1 (dead until agg1 writes it).
// ---------------------------------------------------------------------------
extern "C" void kernel_launch(void* const* d_in, const int* in_sizes, int n_in,
                              void* d_out, int out_size, void* d_ws, size_t ws_size,
                              hipStream_t stream) {
    const float* x  = (const float*)d_in[0];
    const float* W1 = (const float*)d_in[1];
    const float* b1 = (const float*)d_in[2];
    const float* W2 = (const float*)d_in[3];
    const float* b2 = (const float*)d_in[4];
    const float* a  = (const float*)d_in[5];
    const int*   ei = (const int*)d_in[6];
    float* out = (float*)d_out;

    char* ws = (char*)d_ws;
    size_t off = 0;
    auto carve = [&](size_t bytes) -> char* {
        char* p = ws + off;
        off = (off + bytes + 255) & ~(size_t)255;
        return p;
    };
    int*      cnt  = (int*)carve((size_t)NN * 4);
    int*      ecw  = (int*)carve((size_t)NN * CAP * 4);
    _Float16* wp   = (_Float16*)carve((size_t)4 * 65536 * 2);
    _Float16* h    = (_Float16*)carve((size_t)NN * FF * 2);
    _Float16* h1   = (_Float16*)carve((size_t)NN * FF * 2);
    _Float16* xh   = h1;                      // alias: xh dead once agg1 runs

    hipMemsetAsync(cnt, 0, (size_t)NN * 4, stream);

    // packw (64) + x->fp16 cvt (6250) + count+fill (3125), all LDS-free
    packw_kernel<<<64 + XCVT_BLKS + FILL_BLKS, 256, 0, stream>>>(
        W1, W2, wp, x, xh, ei, cnt, ecw);

    // layer 1: GEMM (fp16 A = xh) with dinv-scaled epilogue -> agg (fp16 out)
    gemm_kernel<<<GEMM_BLKS, 512, 0, stream>>>(xh, wp, wp + 65536, h, cnt);
    agg_kernel<_Float16><<<(NN + 3) / 4, 256, 0, stream>>>(h, cnt, ecw, b1, a, h1);
    // layer 2: GEMM (fp16 A = h1) -> agg (fp32 out, final)
    gemm_kernel<<<GEMM_BLKS, 512, 0, stream>>>(
        h1, wp + 131072, wp + 131072 + 65536, h, cnt);
    agg_kernel<float><<<(NN + 3) / 4, 256, 0, stream>>>(h, cnt, ecw, b2, a, out);
}

// Round 14
// 319.499 us; speedup vs baseline: 1.0303x; 1.0303x over previous
//
#include <hip/hip_runtime.h>

// Problem constants
#define NN 50000
#define EE 800000
#define FF 256    // IN = HID = PROJ = 256
#define CAP 64    // edge-slot capacity per dst row (max indeg ~35 for this input)
#define GEMM_BLKS 784
#define FILL_BLKS 782   // ceil(EE/1024): 4 edges per thread (atomic MLP)

typedef float    f32x4 __attribute__((ext_vector_type(4)));
typedef _Float16 f16x8 __attribute__((ext_vector_type(8)));
typedef _Float16 f16x4 __attribute__((ext_vector_type(4)));

// ---------------------------------------------------------------------------
// W pack (swizzled LDS-image) + fused count+fill tail blocks.
// Fill tail is 4-edge-batched per thread: 8 ei loads, then 4 INDEPENDENT
// atomicAdd chains in flight, then 4 scatter stores -> 4x MLP on the
// ~700-900cy atomic-return latency (round-13 showed VALUBusy 0.7%: pure
// latency idle). h'-scaling trick: records carry only src; no dinv needed.
// ---------------------------------------------------------------------------
__global__ void packw_kernel(const float* __restrict__ W1, const float* __restrict__ W2,
                             _Float16* __restrict__ wp,
                             const int* __restrict__ ei, int* __restrict__ cnt,
                             int* __restrict__ ecw) {
    if (blockIdx.x >= 64) {                     // fused count+fill tail
        int base = (blockIdx.x - 64) * 1024 + threadIdx.x;
        int e0 = base, e1 = base + 256, e2 = base + 512, e3 = base + 768;
        bool v0 = e0 < EE, v1 = e1 < EE, v2 = e2 < EE, v3 = e3 < EE;
        int s0 = 0, s1 = 0, s2 = 0, s3 = 0;
        int d0 = 0, d1 = 0, d2 = 0, d3 = 0;
        if (v0) { s0 = ei[e0]; d0 = ei[EE + e0]; }
        if (v1) { s1 = ei[e1]; d1 = ei[EE + e1]; }
        if (v2) { s2 = ei[e2]; d2 = ei[EE + e2]; }
        if (v3) { s3 = ei[e3]; d3 = ei[EE + e3]; }
        int t0 = CAP, t1 = CAP, t2 = CAP, t3 = CAP;
        if (v0) t0 = atomicAdd(&cnt[d0], 1);    // 4 independent chains
        if (v1) t1 = atomicAdd(&cnt[d1], 1);
        if (v2) t2 = atomicAdd(&cnt[d2], 1);
        if (v3) t3 = atomicAdd(&cnt[d3], 1);
        if (t0 < CAP) ecw[(size_t)d0 * CAP + t0] = s0;
        if (t1 < CAP) ecw[(size_t)d1 * CAP + t1] = s1;
        if (t2 < CAP) ecw[(size_t)d2 * CAP + t2] = s2;
        if (t3 < CAP) ecw[(size_t)d3 * CAP + t3] = s3;
        return;                                 // whole block: no barriers
    }
    int idx = blockIdx.x * 256 + threadIdx.x;   // 0..16383
    int p   = idx & 511;
    int kt  = (idx >> 9) & 7;
    int nb  = (idx >> 12) & 1;
    int L   = (idx >> 13) & 1;
    const float* W = L ? W2 : W1;
    int rs = p >> 2, cs = p & 3;
    int r  = rs ^ ((rs >> 2) & 1);
    int c  = cs ^ (r & 3);
    int n  = nb * 128 + r;
    int k0 = kt * 32 + c * 8;
    f16x8 hi, lo;
#pragma unroll
    for (int j = 0; j < 8; ++j) {
        float v = W[(size_t)(k0 + j) * 256 + n];
        _Float16 h = (_Float16)v;
        hi[j] = h;
        lo[j] = (_Float16)(v - (float)h);
    }
    size_t ch = ((size_t)((L * 2 + 0) * 2 + nb) * 8 + kt) * 4096;
    size_t cl = ((size_t)((L * 2 + 1) * 2 + nb) * 8 + kt) * 4096;
    *(f16x8*)(wp + ch + (size_t)p * 8) = hi;
    *(f16x8*)(wp + cl + (size_t)p * 8) = lo;
}

// ---------------------------------------------------------------------------
// GEMM, unified fp16-in-LDS form (round-12 champion structure, unchanged).
// Epilogue scales output row m by dinv[m] = rsqrtf(cnt[m]+1):
// H holds h' = dinv * (X@W), so aggregation is a pure unweighted gather-sum.
// ---------------------------------------------------------------------------

__device__ __forceinline__ void gll16(const void* g, void* l) {
    __builtin_amdgcn_global_load_lds(
        (const __attribute__((address_space(1))) void*)g,
        (__attribute__((address_space(3))) void*)l, 16, 0, 0);
}

template<typename AT>
__global__ __launch_bounds__(512) void gemm_kernel(
    const AT* __restrict__ X, const _Float16* __restrict__ Bhi,
    const _Float16* __restrict__ Blo, _Float16* __restrict__ H,
    const int* __restrict__ cnt) {
    __shared__ __align__(16) _Float16 Bh[2][4096];   // 16 KB
    __shared__ __align__(16) _Float16 Bl[2][4096];   // 16 KB
    __shared__ __align__(16) _Float16 As[2][4096];   // 16 KB (fp16 always)

    // de-swizzle linear gemm id -> (pair p, member nb) with same-XCD pairing
    const int gid = blockIdx.x;
    const int p_  = (gid >> 4) * 8 + (gid & 7);
    const int nb  = (gid >> 3) & 1;
    if (p_ >= 391) return;

    const int tid = threadIdx.x;
    const int ln  = tid & 63;
    const int w   = tid >> 6;        // 0..7
    const int wm  = w & 1;           // 2 x 64 rows
    const int wn  = w >> 1;          // 4 x 32 cols
    const int q   = ln >> 4;         // k-group
    const int l16 = ln & 15;
    const int m0  = p_ * 128;
    const size_t bchunk = (size_t)nb * 8 * 4096;

    // A staging geometry: granule g holds row r_, col-granule c_ of the
    // swizzled fp16 image, stored linearly at g*16B.
    const int g   = w * 64 + ln;                  // granule 0..511
    const int rs_ = g >> 2, cs_ = g & 3;
    const int r_  = rs_ ^ ((rs_ >> 2) & 1);
    const int c_  = cs_ ^ (r_ & 3);
    int gm_ = m0 + r_; if (gm_ > NN - 1) gm_ = NN - 1;

    f32x4 acc[4][2] = {};            // [mt][nt]

    auto stageB = [&](int kt, int buf) {
        gll16(Bhi + bchunk + (size_t)kt * 4096 + (size_t)g * 8,
              &Bh[buf][w * 512]);
        gll16(Blo + bchunk + (size_t)kt * 4096 + (size_t)g * 8,
              &Bl[buf][w * 512]);
    };
    auto stageA16 = [&](int kt, int buf) {
        gll16((const _Float16*)X + (size_t)gm_ * FF + kt * 32 + c_ * 8,
              (_Float16*)&As[buf][0] + (size_t)(w * 64) * 8);
    };
    auto loadA32 = [&](int kt, f32x4& v0, f32x4& v1) {
        const float* p = (const float*)X + (size_t)gm_ * FF + kt * 32 + c_ * 8;
        v0 = *(const f32x4*)p;
        v1 = *(const f32x4*)(p + 4);
    };
    auto writeA32 = [&](int buf, f32x4 v0, f32x4 v1) {
        f16x8 a;
        a[0] = (_Float16)v0.x; a[1] = (_Float16)v0.y;
        a[2] = (_Float16)v0.z; a[3] = (_Float16)v0.w;
        a[4] = (_Float16)v1.x; a[5] = (_Float16)v1.y;
        a[6] = (_Float16)v1.z; a[7] = (_Float16)v1.w;
        *(f16x8*)(&As[buf][(size_t)g * 8]) = a;   // linear, conflict-free
    };

    auto compute = [&](int buf) {
        f16x8 af[4], bhf[2], blf[2];
#pragma unroll
        for (int mt = 0; mt < 4; ++mt) {
            int r  = wm * 64 + mt * 16 + l16;
            int rr = r ^ ((r >> 2) & 1);
            af[mt] = *(const f16x8*)(&As[buf][(rr * 4 + (q ^ (r & 3))) * 8]);
        }
#pragma unroll
        for (int nt = 0; nt < 2; ++nt) {
            int r  = wn * 32 + nt * 16 + l16;
            int rr = r ^ ((r >> 2) & 1);
            int off = (rr * 4 + (q ^ (r & 3))) * 8;
            bhf[nt] = *(const f16x8*)(&Bh[buf][off]);
            blf[nt] = *(const f16x8*)(&Bl[buf][off]);
        }
#pragma unroll
        for (int mt = 0; mt < 4; ++mt)
#pragma unroll
            for (int nt = 0; nt < 2; ++nt) {
                acc[mt][nt] = __builtin_amdgcn_mfma_f32_16x16x32_f16(af[mt], bhf[nt], acc[mt][nt], 0, 0, 0);
                acc[mt][nt] = __builtin_amdgcn_mfma_f32_16x16x32_f16(af[mt], blf[nt], acc[mt][nt], 0, 0, 0);
            }
    };

    int cur = 0;
    if constexpr (sizeof(AT) == 4) {
        f32x4 v0, v1;
        loadA32(0, v0, v1);
        stageB(0, 0);
        writeA32(0, v0, v1);
        __syncthreads();                 // buf0 ready (vmem drained)
#pragma unroll
        for (int kt = 0; kt < 8; ++kt) {
            f32x4 n0, n1;
            if (kt < 7) {
                loadA32(kt + 1, n0, n1); // issue EARLY: hides under MFMAs
                stageB(kt + 1, cur ^ 1);
            }
            compute(cur);
            if (kt < 7) writeA32(cur ^ 1, n0, n1);  // write LATE
            __syncthreads();
            cur ^= 1;
        }
    } else {
        stageA16(0, 0);
        stageB(0, 0);
        __syncthreads();
#pragma unroll
        for (int kt = 0; kt < 8; ++kt) {
            if (kt < 7) { stageA16(kt + 1, cur ^ 1); stageB(kt + 1, cur ^ 1); }
            compute(cur);
            __syncthreads();
            cur ^= 1;
        }
    }

    // epilogue: row-major H, each row m scaled by dinv[m] = rsqrt(cnt[m]+1)
#pragma unroll
    for (int mt = 0; mt < 4; ++mt)
#pragma unroll
        for (int r4 = 0; r4 < 4; ++r4) {
            int m = m0 + wm * 64 + mt * 16 + q * 4 + r4;
            if (m < NN) {
                float sc = rsqrtf((float)(cnt[m] + 1));
#pragma unroll
                for (int nt = 0; nt < 2; ++nt) {
                    int n = nb * 128 + wn * 32 + nt * 16 + l16;
                    H[(size_t)m * FF + n] = (_Float16)(acc[mt][nt][r4] * sc);
                }
            }
        }
}

// ---------------------------------------------------------------------------
// Aggregation + bias + PReLU (round-12 passing form, unchanged).
// H holds h' = dinv*h; records are src-only; di = rsqrt(cnt[i]+1).
// ---------------------------------------------------------------------------
template<typename OT>
__global__ __launch_bounds__(256) void agg_kernel(
    const _Float16* __restrict__ H, const int* __restrict__ cnt,
    const int* __restrict__ ecw, const float* __restrict__ bias,
    const float* __restrict__ a_ptr, OT* __restrict__ out) {
    const int row  = blockIdx.x * 4 + (threadIdx.x >> 6);
    const int lane = threadIdx.x & 63;
    if (row >= NN) return;

    const float av  = a_ptr[0];
    const int   deg = cnt[row];
    const float di  = rsqrtf((float)(deg + 1));
    const int   end = (deg < CAP) ? deg : CAP;
    const int*  er  = ecw + (size_t)row * CAP;

    f16x4 hv = *(const f16x4*)(H + (size_t)row * FF + lane * 4);
    float ax = (float)hv.x;
    float ay = (float)hv.y;
    float az = (float)hv.z;
    float aw = (float)hv.w;

    int e = 0;
    for (; e + 7 < end; e += 8) {               // 8 gathers in flight
        int4 q0 = *(const int4*)(er + e);
        int4 q1 = *(const int4*)(er + e + 4);
        f16x4 h0 = *(const f16x4*)(H + (size_t)q0.x * FF + lane * 4);
        f16x4 h1 = *(const f16x4*)(H + (size_t)q0.y * FF + lane * 4);
        f16x4 h2 = *(const f16x4*)(H + (size_t)q0.z * FF + lane * 4);
        f16x4 h3 = *(const f16x4*)(H + (size_t)q0.w * FF + lane * 4);
        f16x4 h4 = *(const f16x4*)(H + (size_t)q1.x * FF + lane * 4);
        f16x4 h5 = *(const f16x4*)(H + (size_t)q1.y * FF + lane * 4);
        f16x4 h6 = *(const f16x4*)(H + (size_t)q1.z * FF + lane * 4);
        f16x4 h7 = *(const f16x4*)(H + (size_t)q1.w * FF + lane * 4);
        ax += ((float)h0.x + (float)h1.x) + ((float)h2.x + (float)h3.x)
            + ((float)h4.x + (float)h5.x) + ((float)h6.x + (float)h7.x);
        ay += ((float)h0.y + (float)h1.y) + ((float)h2.y + (float)h3.y)
            + ((float)h4.y + (float)h5.y) + ((float)h6.y + (float)h7.y);
        az += ((float)h0.z + (float)h1.z) + ((float)h2.z + (float)h3.z)
            + ((float)h4.z + (float)h5.z) + ((float)h6.z + (float)h7.z);
        aw += ((float)h0.w + (float)h1.w) + ((float)h2.w + (float)h3.w)
            + ((float)h4.w + (float)h5.w) + ((float)h6.w + (float)h7.w);
    }
    for (; e + 3 < end; e += 4) {               // 4-deep remainder
        int4 q0 = *(const int4*)(er + e);
        f16x4 h0 = *(const f16x4*)(H + (size_t)q0.x * FF + lane * 4);
        f16x4 h1 = *(const f16x4*)(H + (size_t)q0.y * FF + lane * 4);
        f16x4 h2 = *(const f16x4*)(H + (size_t)q0.z * FF + lane * 4);
        f16x4 h3 = *(const f16x4*)(H + (size_t)q0.w * FF + lane * 4);
        ax += ((float)h0.x + (float)h1.x) + ((float)h2.x + (float)h3.x);
        ay += ((float)h0.y + (float)h1.y) + ((float)h2.y + (float)h3.y);
        az += ((float)h0.z + (float)h1.z) + ((float)h2.z + (float)h3.z);
        aw += ((float)h0.w + (float)h1.w) + ((float)h2.w + (float)h3.w);
    }
    for (; e < end; ++e) {
        int s = er[e];
        f16x4 h0 = *(const f16x4*)(H + (size_t)s * FF + lane * 4);
        ax += (float)h0.x;
        ay += (float)h0.y;
        az += (float)h0.z;
        aw += (float)h0.w;
    }

    f32x4 bv = *(const f32x4*)(bias + lane * 4);
    float r0 = di * ax + bv.x; r0 = (r0 >= 0.f) ? r0 : av * r0;
    float r1 = di * ay + bv.y; r1 = (r1 >= 0.f) ? r1 : av * r1;
    float r2 = di * az + bv.z; r2 = (r2 >= 0.f) ? r2 : av * r2;
    float r3 = di * aw + bv.w; r3 = (r3 >= 0.f) ? r3 : av * r3;
    if constexpr (sizeof(OT) == 4) {
        f32x4 res = {r0, r1, r2, r3};
        *(f32x4*)((float*)out + (size_t)row * FF + lane * 4) = res;
    } else {
        f16x4 res;
        res.x = (_Float16)r0; res.y = (_Float16)r1;
        res.z = (_Float16)r2; res.w = (_Float16)r3;
        *(f16x4*)((_Float16*)out + (size_t)row * FF + lane * 4) = res;
    }
}

// ---------------------------------------------------------------------------
// Launch: 5 kernels + 1 memset (round-12 structure).
// ---------------------------------------------------------------------------
extern "C" void kernel_launch(void* const* d_in, const int* in_sizes, int n_in,
                              void* d_out, int out_size, void* d_ws, size_t ws_size,
                              hipStream_t stream) {
    const float* x  = (const float*)d_in[0];
    const float* W1 = (const float*)d_in[1];
    const float* b1 = (const float*)d_in[2];
    const float* W2 = (const float*)d_in[3];
    const float* b2 = (const float*)d_in[4];
    const float* a  = (const float*)d_in[5];
    const int*   ei = (const int*)d_in[6];
    float* out = (float*)d_out;

    char* ws = (char*)d_ws;
    size_t off = 0;
    auto carve = [&](size_t bytes) -> char* {
        char* p = ws + off;
        off = (off + bytes + 255) & ~(size_t)255;
        return p;
    };
    int*      cnt  = (int*)carve((size_t)NN * 4);
    int*      ecw  = (int*)carve((size_t)NN * CAP * 4);
    _Float16* wp   = (_Float16*)carve((size_t)4 * 65536 * 2);
    _Float16* h    = (_Float16*)carve((size_t)NN * FF * 2);
    _Float16* h1   = (_Float16*)carve((size_t)NN * FF * 2);

    hipMemsetAsync(cnt, 0, (size_t)NN * 4, stream);

    // packw (64 blocks) fused with 4-batched count+fill (782 tail blocks)
    packw_kernel<<<64 + FILL_BLKS, 256, 0, stream>>>(W1, W2, wp, ei, cnt, ecw);

    // layer 1: GEMM (fp32 A, reg-staged cvt) with dinv epilogue -> agg (fp16)
    gemm_kernel<float><<<GEMM_BLKS, 512, 0, stream>>>(x, wp, wp + 65536, h, cnt);
    agg_kernel<_Float16><<<(NN + 3) / 4, 256, 0, stream>>>(h, cnt, ecw, b1, a, h1);
    // layer 2: GEMM (fp16 A) -> agg (fp32 out, final)
    gemm_kernel<_Float16><<<GEMM_BLKS, 512, 0, stream>>>(
        h1, wp + 131072, wp + 131072 + 65536, h, cnt);
    agg_kernel<float><<<(NN + 3) / 4, 256, 0, stream>>>(h, cnt, ecw, b2, a, out);
}